// Round 1
// baseline (1952.132 us; speedup 1.0000x reference)
//
#include <hip/hip_runtime.h>
#include <math.h>

#define BATCH 256
#define SEQ   2048
#define HID   128
#define NTHR  512

typedef float v2f __attribute__((ext_vector_type(2)));

// One block per batch element. Thread (j = tid&127, q = tid>>7) computes the
// k-quarter [q*32, q*32+32) of output neuron j for both matvecs of both layers.
// All 4 weight matrices live in VGPRs (128 VGPR/thread as packed f32 pairs).
// h is double-buffered in LDS; 4 barriers per time step.
__global__ __launch_bounds__(NTHR, 2) void rnn_persist_kernel(
    const int*   __restrict__ x,        // [B, T]
    const int*   __restrict__ lengths,  // [B]
    const float* __restrict__ emb,      // [VOCAB, H]
    const float* __restrict__ W_ih,     // [2, H, H]
    const float* __restrict__ W_hh,     // [2, H, H]
    const float* __restrict__ bias,     // [2, H]
    const float* __restrict__ cls_w,    // [H]
    const float* __restrict__ cls_b,    // [1]
    float*       __restrict__ out)      // [B]
{
    const int b   = blockIdx.x;
    const int tid = threadIdx.x;
    const int j   = tid & (HID - 1);
    const int q   = tid >> 7;          // 0..3
    const int k0  = q * 32;

    __shared__ int                    xids[SEQ];       // 8 KB
    __shared__ __align__(16) float    xrow[HID];       // current emb row
    __shared__ __align__(16) float    h0[2][HID];      // layer-0 hidden, dbuf
    __shared__ __align__(16) float    h1[2][HID];      // layer-1 hidden, dbuf
    __shared__ __align__(16) float    part[4][HID];    // k-quarter partials

    const int len = lengths[b];

    // stage token ids for this sequence
    for (int i = tid; i < SEQ; i += NTHR) xids[i] = x[b * SEQ + i];

    // load this thread's weight slice into registers (coalesced across lanes:
    // for fixed k, lanes j..j+63 read consecutive floats)
    v2f wih0[16], whh0[16], wih1[16], whh1[16];
#pragma unroll
    for (int i = 0; i < 16; ++i) {
        const int k = k0 + 2 * i;
        wih0[i] = v2f{W_ih[(0 * HID + k) * HID + j], W_ih[(0 * HID + k + 1) * HID + j]};
        whh0[i] = v2f{W_hh[(0 * HID + k) * HID + j], W_hh[(0 * HID + k + 1) * HID + j]};
        wih1[i] = v2f{W_ih[(1 * HID + k) * HID + j], W_ih[(1 * HID + k + 1) * HID + j]};
        whh1[i] = v2f{W_hh[(1 * HID + k) * HID + j], W_hh[(1 * HID + k + 1) * HID + j]};
    }
    const float b0 = bias[j];
    const float b1 = bias[HID + j];

    if (tid < HID) {
        h0[0][tid] = 0.f; h0[1][tid] = 0.f;
        h1[0][tid] = 0.f; h1[1][tid] = 0.f;
    }
    __syncthreads();                       // xids + h ready
    if (tid < HID) xrow[tid] = emb[xids[0] * HID + tid];
    __syncthreads();

    int p = 0;
    for (int t = 0; t < len; ++t) {
        // prefetch next step's embedding row (latency covered by both layers)
        float nf = 0.f;
        const int tn = (t + 1 < len) ? (t + 1) : t;
        if (tid < HID) nf = emb[xids[tn] * HID + tid];

        // ---------- layer 0: partials ----------
        {
            v2f acc = {0.f, 0.f};
            const v2f* xin = (const v2f*)&xrow[k0];
            const v2f* hin = (const v2f*)&h0[p][k0];
#pragma unroll
            for (int i = 0; i < 16; ++i) {
                acc = __builtin_elementwise_fma(xin[i], wih0[i], acc);
                acc = __builtin_elementwise_fma(hin[i], whh0[i], acc);
            }
            part[q][j] = acc.x + acc.y;
        }
        __syncthreads();
        if (tid < HID) {
            const float z = part[0][j] + part[1][j] + part[2][j] + part[3][j] + b0;
            h0[p ^ 1][j] = tanhf(z);
        }
        __syncthreads();

        // ---------- layer 1: partials ----------
        {
            v2f acc = {0.f, 0.f};
            const v2f* xin = (const v2f*)&h0[p ^ 1][k0];
            const v2f* hin = (const v2f*)&h1[p][k0];
#pragma unroll
            for (int i = 0; i < 16; ++i) {
                acc = __builtin_elementwise_fma(xin[i], wih1[i], acc);
                acc = __builtin_elementwise_fma(hin[i], whh1[i], acc);
            }
            part[q][j] = acc.x + acc.y;
        }
        __syncthreads();
        if (tid < HID) {
            const float z = part[0][j] + part[1][j] + part[2][j] + part[3][j] + b1;
            h1[p ^ 1][j] = tanhf(z);
            xrow[j] = nf;              // publish prefetched emb row for t+1
        }
        __syncthreads();
        p ^= 1;
    }

    // classifier head: out[b] = sigmoid(h1 . cls_w + cls_b)
    if (tid < HID) part[0][j] = h1[p][j] * cls_w[j];
    __syncthreads();
    if (tid == 0) {
        float s = 0.f;
        for (int i = 0; i < HID; ++i) s += part[0][i];
        s += cls_b[0];
        out[b] = 1.f / (1.f + expf(-s));
    }
}

extern "C" void kernel_launch(void* const* d_in, const int* in_sizes, int n_in,
                              void* d_out, int out_size, void* d_ws, size_t ws_size,
                              hipStream_t stream) {
    const int*   x       = (const int*)  d_in[0];
    const int*   lengths = (const int*)  d_in[1];
    const float* emb     = (const float*)d_in[2];
    const float* W_ih    = (const float*)d_in[3];
    const float* W_hh    = (const float*)d_in[4];
    const float* bias    = (const float*)d_in[5];
    const float* cls_w   = (const float*)d_in[6];
    const float* cls_b   = (const float*)d_in[7];
    float*       out     = (float*)      d_out;

    rnn_persist_kernel<<<BATCH, NTHR, 0, stream>>>(
        x, lengths, emb, W_ih, W_hh, bias, cls_w, cls_b, out);
}

// Round 2
// 1545.380 us; speedup vs baseline: 1.2632x; 1.2632x over previous
//
#include <hip/hip_runtime.h>
#include <math.h>

#define BATCH 256
#define SEQ   2048
#define HID   128
#define NTHR  512
#define PADH  144   // 128 floats + 4-float pad per 32-float chunk (bank stagger)

typedef float v2f __attribute__((ext_vector_type(2)));

#if __has_builtin(__builtin_amdgcn_update_dpp)
template<int CTRL>
__device__ __forceinline__ float dpp_movf(float x) {
    return __builtin_bit_cast(float,
        __builtin_amdgcn_update_dpp(0, __builtin_bit_cast(int, x),
                                    CTRL, 0xF, 0xF, false));
}
__device__ __forceinline__ float quad_reduce(float x) {
    x += dpp_movf<0xB1>(x);   // quad_perm [1,0,3,2]: + lane^1
    x += dpp_movf<0x4E>(x);   // quad_perm [2,3,0,1]: + lane^2
    return x;                 // full sum in all 4 lanes of the quad
}
#else
__device__ __forceinline__ float quad_reduce(float x) {
    x += __shfl_xor(x, 1, 4);
    x += __shfl_xor(x, 2, 4);
    return x;
}
#endif

__device__ __forceinline__ float fast_rcp(float x) {
#if __has_builtin(__builtin_amdgcn_rcpf)
    return __builtin_amdgcn_rcpf(x);
#else
    return 1.0f / x;
#endif
}

__device__ __forceinline__ float fast_tanh(float z) {
    // tanh(z) = 1 - 2/(exp(2z)+1); v_exp_f32 + v_rcp_f32, ~1e-6 rel err
    float e = __expf(2.0f * z);
    return 1.0f - 2.0f * fast_rcp(e + 1.0f);
}

// One block per batch row. Thread (j = wave*16 + (lane>>2), q = lane&3) holds
// the k-quarter [32q, 32q+32) of columns j of all 4 weight matrices in VGPRs.
// Software pipeline: phase ph computes h0(ph) AND h1(ph-1) concurrently (both
// depend only on state written at phase ph-1), so ONE barrier per time step.
// k-partials are reduced across the 4 lanes of a quad via DPP (no LDS).
__global__ __launch_bounds__(NTHR, 2) void rnn_pipe_kernel(
    const int*   __restrict__ x,        // [B, T]
    const int*   __restrict__ lengths,  // [B]
    const float* __restrict__ emb,      // [VOCAB, H]
    const float* __restrict__ W_ih,     // [2, H, H]
    const float* __restrict__ W_hh,     // [2, H, H]
    const float* __restrict__ bias,     // [2, H]
    const float* __restrict__ cls_w,    // [H]
    const float* __restrict__ cls_b,    // [1]
    float*       __restrict__ out)      // [B]
{
    const int b    = blockIdx.x;
    const int tid  = threadIdx.x;
    const int wave = tid >> 6;
    const int lane = tid & 63;
    const int j    = wave * 16 + (lane >> 2);
    const int q    = lane & 3;
    const int k0   = q * 32;

    __shared__ int xids[SEQ];                       // 8 KB
    __shared__ __align__(16) float xrow[2][PADH];   // x(t) emb row, dbuf
    __shared__ __align__(16) float h0s[2][PADH];    // layer-0 hidden, dbuf
    __shared__ __align__(16) float h1s[2][PADH];    // layer-1 hidden, dbuf
    __shared__ __align__(16) float red[HID];        // classifier reduce

    const int len = lengths[b];

    for (int i = tid; i < SEQ; i += NTHR) xids[i] = x[b * SEQ + i];

    // weight slices -> VGPRs (v2f packs along k)
    v2f wih0[16], whh0[16], wih1[16], whh1[16];
#pragma unroll
    for (int i = 0; i < 16; ++i) {
        const int k = k0 + 2 * i;
        wih0[i] = v2f{W_ih[k * HID + j],           W_ih[(k + 1) * HID + j]};
        whh0[i] = v2f{W_hh[k * HID + j],           W_hh[(k + 1) * HID + j]};
        wih1[i] = v2f{W_ih[(HID + k) * HID + j],   W_ih[(HID + k + 1) * HID + j]};
        whh1[i] = v2f{W_hh[(HID + k) * HID + j],   W_hh[(HID + k + 1) * HID + j]};
    }
    const float b0 = bias[j];
    const float b1 = bias[HID + j];

    if (tid < HID) {
        const int jj = tid + ((tid >> 5) << 2);     // padded index
        h0s[0][jj] = 0.f; h0s[1][jj] = 0.f;
        h1s[0][jj] = 0.f; h1s[1][jj] = 0.f;
    }
    __syncthreads();                                // xids + zeros visible
    if (tid < HID) {
        const int jj = tid + ((tid >> 5) << 2);
        xrow[0][jj] = emb[xids[0] * HID + tid];
    }
    __syncthreads();

    int p = 0;
    for (int ph = 0; ph <= len; ++ph) {
        // prefetch x(ph+1) emb row: one load per wave (16 lanes each)
        float nf = 0.f;
        const int li = wave * 16 + lane;            // valid when lane<16
        if (lane < 16) {
            const int tn = (ph + 1 < len) ? (ph + 1) : (len - 1);
            nf = emb[xids[tn] * HID + li];
        }

        // broadcast reads: chunk q starts at float q*36 (bank-staggered)
        const float4* xr  = (const float4*)xrow[p] + q * 9;
        const float4* h0r = (const float4*)h0s[p]  + q * 9;
        const float4* h1r = (const float4*)h1s[p]  + q * 9;

        v2f s0a{0,0}, s0b{0,0}, s0c{0,0}, s0d{0,0};
        v2f s1a{0,0}, s1b{0,0}, s1c{0,0}, s1d{0,0};
#pragma unroll
        for (int i = 0; i < 8; ++i) {
            const float4 xq = xr[i];
            const float4 hq = h0r[i];
            const float4 gq = h1r[i];
            const v2f xlo{xq.x, xq.y}, xhi{xq.z, xq.w};
            const v2f hlo{hq.x, hq.y}, hhi{hq.z, hq.w};
            const v2f glo{gq.x, gq.y}, ghi{gq.z, gq.w};
            s0a = __builtin_elementwise_fma(xlo, wih0[2*i],   s0a);
            s0b = __builtin_elementwise_fma(xhi, wih0[2*i+1], s0b);
            s0c = __builtin_elementwise_fma(hlo, whh0[2*i],   s0c);
            s0d = __builtin_elementwise_fma(hhi, whh0[2*i+1], s0d);
            s1a = __builtin_elementwise_fma(hlo, wih1[2*i],   s1a);
            s1b = __builtin_elementwise_fma(hhi, wih1[2*i+1], s1b);
            s1c = __builtin_elementwise_fma(glo, whh1[2*i],   s1c);
            s1d = __builtin_elementwise_fma(ghi, whh1[2*i+1], s1d);
        }
        const v2f s0v = (s0a + s0b) + (s0c + s0d);
        const v2f s1v = (s1a + s1b) + (s1c + s1d);
        const float t0 = fast_tanh(quad_reduce(s0v.x + s0v.y) + b0);
        const float t1 = fast_tanh(quad_reduce(s1v.x + s1v.y) + b1);

        if (q == 0) {
            const int jj = j + ((j >> 5) << 2);
            if (ph < len) h0s[p ^ 1][jj] = t0;      // h0(ph)
            if (ph >= 1)  h1s[p ^ 1][jj] = t1;      // h1(ph-1)
        }
        if (lane < 16) {
            const int jj = li + ((li >> 5) << 2);
            xrow[p ^ 1][jj] = nf;
        }
        __syncthreads();
        p ^= 1;
    }

    // classifier: out[b] = sigmoid(h1(len-1) . cls_w + cls_b)
    if (tid < HID) {
        const int jj = tid + ((tid >> 5) << 2);
        red[tid] = h1s[p][jj] * cls_w[tid];
    }
    __syncthreads();
    if (tid == 0) {
        float s = 0.f;
        for (int i = 0; i < HID; ++i) s += red[i];
        s += cls_b[0];
        out[b] = fast_rcp(1.0f + __expf(-s));
    }
}

extern "C" void kernel_launch(void* const* d_in, const int* in_sizes, int n_in,
                              void* d_out, int out_size, void* d_ws, size_t ws_size,
                              hipStream_t stream) {
    const int*   x       = (const int*)  d_in[0];
    const int*   lengths = (const int*)  d_in[1];
    const float* emb     = (const float*)d_in[2];
    const float* W_ih    = (const float*)d_in[3];
    const float* W_hh    = (const float*)d_in[4];
    const float* bias    = (const float*)d_in[5];
    const float* cls_w   = (const float*)d_in[6];
    const float* cls_b   = (const float*)d_in[7];
    float*       out     = (float*)      d_out;

    rnn_pipe_kernel<<<BATCH, NTHR, 0, stream>>>(
        x, lengths, emb, W_ih, W_hh, bias, cls_w, cls_b, out);
}

// Round 3
// 1195.317 us; speedup vs baseline: 1.6331x; 1.2929x over previous
//
#include <hip/hip_runtime.h>
#include <math.h>

#define BATCH 256
#define SEQ   2048
#define HID   128
#define NTHR  512

typedef _Float16 v2h __attribute__((ext_vector_type(2)));

// ---- cross-lane quad reduce (sum over 4 lanes of each quad) via DPP ----
template<int CTRL>
__device__ __forceinline__ float dpp_movf(float x) {
    return __builtin_bit_cast(float,
        __builtin_amdgcn_update_dpp(0, __builtin_bit_cast(int, x),
                                    CTRL, 0xF, 0xF, false));
}
__device__ __forceinline__ float quad_reduce(float x) {
    x += dpp_movf<0xB1>(x);   // quad_perm [1,0,3,2]
    x += dpp_movf<0x4E>(x);   // quad_perm [2,3,0,1]
    return x;
}
__device__ __forceinline__ float fast_rcp(float x) {
    return __builtin_amdgcn_rcpf(x);
}
__device__ __forceinline__ float fast_tanh(float z) {
    float e = __expf(2.0f * z);               // v_exp_f32 path
    return 1.0f - 2.0f * fast_rcp(e + 1.0f);  // exact at +-inf
}
__device__ __forceinline__ float dot2(v2h a, v2h b, float c) {
#if __has_builtin(__builtin_amdgcn_fdot2)
    return __builtin_amdgcn_fdot2(a, b, c, false);   // v_dot2_f32_f16
#else
    return c + (float)a.x * (float)b.x + (float)a.y * (float)b.y;
#endif
}
#define BC(u) __builtin_bit_cast(v2h, (u))

// One block per batch row. wave = tid>>6, lane = tid&63.
// Thread (j = wave*16 + (lane>>2), q = lane&3) owns k-range [32q,32q+32) of
// weight columns j for all 4 matvecs (f16 weights in VGPRs, 64 regs).
// State (xrow/h0/h1) stored f16 in LDS, double-buffered; compute via
// v_dot2_f32_f16 with f32 accumulate; quad DPP reduce; 1 barrier/phase.
// Pipeline: phase ph computes h0(ph) and h1(ph-1).
// Embedding rows prefetched via a depth-2 register ring (loop unrolled x2).
__global__ __launch_bounds__(NTHR, 2) void rnn_f16_kernel(
    const int*   __restrict__ x,        // [B, T]
    const int*   __restrict__ lengths,  // [B]
    const float* __restrict__ emb,      // [VOCAB, H]
    const float* __restrict__ W_ih,     // [2, H, H]
    const float* __restrict__ W_hh,     // [2, H, H]
    const float* __restrict__ bias,     // [2, H]
    const float* __restrict__ cls_w,    // [H]
    const float* __restrict__ cls_b,    // [1]
    float*       __restrict__ out)      // [B]
{
    const int b    = blockIdx.x;
    const int tid  = threadIdx.x;
    const int wave = tid >> 6;
    const int lane = tid & 63;
    const int j    = wave * 16 + (lane >> 2);
    const int q    = lane & 3;
    const int k0   = q * 32;
    const int q4   = q * 4;              // uint4 offset into a 128-f16 row

    __shared__ int xids[SEQ];                          // 8 KB
    __shared__ __align__(16) _Float16 xrowh[2][HID];
    __shared__ __align__(16) _Float16 h0h[2][HID];
    __shared__ __align__(16) _Float16 h1h[2][HID];
    __shared__ __align__(16) float    red[HID];

    const int len   = lengths[b];
    const int lenm1 = len - 1;
    const float4* embf4 = (const float4*)emb;          // row stride 32

    for (int i = tid; i < SEQ; i += NTHR) xids[i] = x[b * SEQ + i];
    if (tid < HID) {
        h0h[0][tid] = (_Float16)0.f; h0h[1][tid] = (_Float16)0.f;
        h1h[0][tid] = (_Float16)0.f; h1h[1][tid] = (_Float16)0.f;
    }
    __syncthreads();                                   // xids + zeros visible

    // prologue global loads: emb rows for tok 0 (direct) + ring tok1, tok2
    float4 r0 = {0,0,0,0}, rA = {0,0,0,0}, rB = {0,0,0,0};
    if (tid < 32) {
        r0 = embf4[(size_t)xids[0] * 32 + tid];
        rA = embf4[(size_t)xids[min(1, lenm1)] * 32 + tid];
        rB = embf4[(size_t)xids[min(2, lenm1)] * 32 + tid];
    }

    // weight slices -> f16 VGPRs (one-time cost)
    v2h wih0[16], whh0[16], wih1[16], whh1[16];
#pragma unroll
    for (int i = 0; i < 16; ++i) {
        const int k = k0 + 2 * i;
        wih0[i] = v2h{(_Float16)W_ih[k * HID + j],         (_Float16)W_ih[(k + 1) * HID + j]};
        whh0[i] = v2h{(_Float16)W_hh[k * HID + j],         (_Float16)W_hh[(k + 1) * HID + j]};
        wih1[i] = v2h{(_Float16)W_ih[(HID + k) * HID + j], (_Float16)W_ih[(HID + k + 1) * HID + j]};
        whh1[i] = v2h{(_Float16)W_hh[(HID + k) * HID + j], (_Float16)W_hh[(HID + k + 1) * HID + j]};
    }
    const float b0 = bias[j];
    const float b1 = bias[HID + j];

    if (tid < 32) {
        uint a01 = __builtin_bit_cast(uint, __builtin_amdgcn_cvt_pkrtz(r0.x, r0.y));
        uint a23 = __builtin_bit_cast(uint, __builtin_amdgcn_cvt_pkrtz(r0.z, r0.w));
        ((uint2*)&xrowh[0][0])[tid] = uint2{a01, a23};
    }
    __syncthreads();

    int ph = 0, pf = 0;

#define DO_PHASE(RD, WR, RREG)                                                  \
    {                                                                           \
        uint u01 = 0, u23 = 0;                                                  \
        if (tid < 32) {                                                         \
            u01 = __builtin_bit_cast(uint, __builtin_amdgcn_cvt_pkrtz(RREG.x, RREG.y)); \
            u23 = __builtin_bit_cast(uint, __builtin_amdgcn_cvt_pkrtz(RREG.z, RREG.w)); \
            const int tn = xids[min(ph + 3, lenm1)];                            \
            RREG = embf4[(size_t)tn * 32 + tid];                                \
        }                                                                       \
        float a0 = 0.f, a1 = 0.f, c0 = 0.f, c1 = 0.f;                           \
        const uint4* xr  = (const uint4*)&xrowh[RD][0] + q4;                    \
        const uint4* h0r = (const uint4*)&h0h[RD][0]   + q4;                    \
        const uint4* h1r = (const uint4*)&h1h[RD][0]   + q4;                    \
        _Pragma("unroll")                                                       \
        for (int i = 0; i < 4; ++i) {                                           \
            const uint4 xu = xr[i];                                             \
            const uint4 hu = h0r[i];                                            \
            const uint4 gu = h1r[i];                                            \
            a0 = dot2(BC(xu.x), wih0[4*i+0], a0);                               \
            a0 = dot2(BC(xu.y), wih0[4*i+1], a0);                               \
            a0 = dot2(BC(xu.z), wih0[4*i+2], a0);                               \
            a0 = dot2(BC(xu.w), wih0[4*i+3], a0);                               \
            a1 = dot2(BC(hu.x), whh0[4*i+0], a1);                               \
            a1 = dot2(BC(hu.y), whh0[4*i+1], a1);                               \
            a1 = dot2(BC(hu.z), whh0[4*i+2], a1);                               \
            a1 = dot2(BC(hu.w), whh0[4*i+3], a1);                               \
            c0 = dot2(BC(hu.x), wih1[4*i+0], c0);                               \
            c0 = dot2(BC(hu.y), wih1[4*i+1], c0);                               \
            c0 = dot2(BC(hu.z), wih1[4*i+2], c0);                               \
            c0 = dot2(BC(hu.w), wih1[4*i+3], c0);                               \
            c1 = dot2(BC(gu.x), whh1[4*i+0], c1);                               \
            c1 = dot2(BC(gu.y), whh1[4*i+1], c1);                               \
            c1 = dot2(BC(gu.z), whh1[4*i+2], c1);                               \
            c1 = dot2(BC(gu.w), whh1[4*i+3], c1);                               \
        }                                                                       \
        const float t0 = fast_tanh(quad_reduce(a0 + a1) + b0);                  \
        const float t1 = fast_tanh(quad_reduce(c0 + c1) + b1);                  \
        if (q == 0 && ph < len) h0h[WR][j] = (_Float16)t0;                      \
        if (q == 1 && ph >= 1)  h1h[WR][j] = (_Float16)t1;                      \
        if (tid < 32) ((uint2*)&xrowh[WR][0])[tid] = uint2{u01, u23};           \
        __syncthreads();                                                        \
    }

    for (;;) {
        DO_PHASE(0, 1, rA)
        ++ph;
        if (ph > len) { pf = 1; break; }
        DO_PHASE(1, 0, rB)
        ++ph;
        if (ph > len) { pf = 0; break; }
    }
#undef DO_PHASE

    // classifier: out[b] = sigmoid(h1(len-1) . cls_w + cls_b)
    if (tid < HID) red[tid] = (float)h1h[pf][tid] * cls_w[tid];
    __syncthreads();
    if (tid == 0) {
        float s = 0.f;
        for (int i = 0; i < HID; ++i) s += red[i];
        s += cls_b[0];
        out[b] = fast_rcp(1.0f + __expf(-s));
    }
}

extern "C" void kernel_launch(void* const* d_in, const int* in_sizes, int n_in,
                              void* d_out, int out_size, void* d_ws, size_t ws_size,
                              hipStream_t stream) {
    const int*   x       = (const int*)  d_in[0];
    const int*   lengths = (const int*)  d_in[1];
    const float* emb     = (const float*)d_in[2];
    const float* W_ih    = (const float*)d_in[3];
    const float* W_hh    = (const float*)d_in[4];
    const float* bias    = (const float*)d_in[5];
    const float* cls_w   = (const float*)d_in[6];
    const float* cls_b   = (const float*)d_in[7];
    float*       out     = (float*)      d_out;

    rnn_f16_kernel<<<BATCH, NTHR, 0, stream>>>(
        x, lengths, emb, W_ih, W_hh, bias, cls_w, cls_b, out);
}

// Round 4
// 804.260 us; speedup vs baseline: 2.4272x; 1.4862x over previous
//
#include <hip/hip_runtime.h>
#include <math.h>

#define BATCH 256
#define SEQ   2048
#define HID   128
#define NTHR  512
#define VOCAB 50000

typedef _Float16 v2h __attribute__((ext_vector_type(2)));
typedef _Float16 v8h __attribute__((ext_vector_type(8)));
typedef float    v4f __attribute__((ext_vector_type(4)));

template<int CTRL>
__device__ __forceinline__ float dpp_movf(float x) {
    return __builtin_bit_cast(float,
        __builtin_amdgcn_update_dpp(0, __builtin_bit_cast(int, x),
                                    CTRL, 0xF, 0xF, false));
}
__device__ __forceinline__ float quad_reduce(float x) {
    x += dpp_movf<0xB1>(x);   // + lane^1
    x += dpp_movf<0x4E>(x);   // + lane^2
    return x;
}
__device__ __forceinline__ float fast_rcp(float x) { return __builtin_amdgcn_rcpf(x); }
__device__ __forceinline__ float fast_tanh(float z) {
    float e = __expf(2.0f * z);
    return 1.0f - 2.0f * fast_rcp(e + 1.0f);
}
__device__ __forceinline__ float dot2(v2h a, v2h b, float c) {
    return __builtin_amdgcn_fdot2(a, b, c, false);
}
#define BCH(u) __builtin_bit_cast(v2h, (u))
#define BC8(u) __builtin_bit_cast(v8h, (u))

// ---------------- Y = emb @ W_ih[0] + b[0]  (f16 out) ----------------
// Same dot2/quad-reduce scheme as the R3 recurrent kernel, one row at a time.
__global__ __launch_bounds__(NTHR, 2) void emb_proj_kernel(
    const float* __restrict__ emb,   // [VOCAB, 128]
    const float* __restrict__ W_ih,  // [2, 128, 128] (layer 0 used)
    const float* __restrict__ bias,  // [2, 128]
    _Float16*    __restrict__ Y)     // [VOCAB, 128]
{
    const int tid  = threadIdx.x;
    const int wave = tid >> 6;
    const int lane = tid & 63;
    const int j    = wave * 16 + (lane >> 2);
    const int q    = lane & 3;

    __shared__ __align__(16) _Float16 xr[HID];

    v2h w[16];
#pragma unroll
    for (int i = 0; i < 16; ++i) {
        const int k = q * 32 + 2 * i;
        w[i] = v2h{(_Float16)W_ih[k * HID + j], (_Float16)W_ih[(k + 1) * HID + j]};
    }
    const float bj = bias[j];
    const float4* embf4 = (const float4*)emb;

    for (int r = blockIdx.x; r < VOCAB; r += gridDim.x) {
        if (tid < 32) {
            float4 v = embf4[(size_t)r * 32 + tid];
            uint a01 = __builtin_bit_cast(uint, __builtin_amdgcn_cvt_pkrtz(v.x, v.y));
            uint a23 = __builtin_bit_cast(uint, __builtin_amdgcn_cvt_pkrtz(v.z, v.w));
            ((uint2*)&xr[0])[tid] = uint2{a01, a23};
        }
        __syncthreads();
        const uint4* xp = (const uint4*)&xr[0] + q * 4;
        float acc = 0.f;
#pragma unroll
        for (int i = 0; i < 4; ++i) {
            const uint4 xu = xp[i];
            acc = dot2(BCH(xu.x), w[4*i+0], acc);
            acc = dot2(BCH(xu.y), w[4*i+1], acc);
            acc = dot2(BCH(xu.z), w[4*i+2], acc);
            acc = dot2(BCH(xu.w), w[4*i+3], acc);
        }
        acc = quad_reduce(acc) + bj;
        if (q == 0) Y[(size_t)r * HID + j] = (_Float16)acc;
        __syncthreads();
    }
}

// ---------------- recurrent kernel: MFMA phases ----------------
// Wave w owns output j-tile [16w, 16w+16) of BOTH layers.
// Phase ph computes h0(ph) = tanh(Y[tok(ph)] + Whh0 h0(ph-1))  and
//                  h1(ph-1) = tanh(Wih1 h0(ph-1) + Whh1 h1(ph-2) + b1).
// A-operand: each lane reads its 8-f16 k-chunk of h from LDS -> all 16 rows
// of A identical (hardware broadcast); MFMA does the k-reduction internally.
// C/D row 0 = reg .x of lanes 0..15 (col = lane&15).
__global__ __launch_bounds__(NTHR, 2) void rnn_mfma_kernel(
    const int*      __restrict__ x,        // [B, T]
    const int*      __restrict__ lengths,  // [B]
    const _Float16* __restrict__ Y,        // [VOCAB, 128] = emb@Wih0 + b0
    const float*    __restrict__ W_ih,     // [2, 128, 128] (layer 1 used)
    const float*    __restrict__ W_hh,     // [2, 128, 128]
    const float*    __restrict__ bias,     // [2, 128] (layer 1 used)
    const float*    __restrict__ cls_w,    // [128]
    const float*    __restrict__ cls_b,    // [1]
    float*          __restrict__ out)      // [B]
{
    const int b    = blockIdx.x;
    const int tid  = threadIdx.x;
    const int wave = tid >> 6;
    const int lane = tid & 63;
    const int kg   = lane >> 4;            // k-group 0..3 (8 f16 each)
    const int jcol = wave * 16 + (lane & 15);

    __shared__ int xids[SEQ];                        // 8 KB
    __shared__ __align__(16) _Float16 h0h[2][HID];
    __shared__ __align__(16) _Float16 h1h[2][HID];
    __shared__ __align__(16) float    red[HID];

    const int len   = lengths[b];
    const int lenm1 = len - 1;

    for (int i = tid; i < SEQ; i += NTHR) xids[i] = x[b * SEQ + i];
    if (tid < HID) {
        h0h[0][tid] = (_Float16)0.f; h0h[1][tid] = (_Float16)0.f;
        h1h[0][tid] = (_Float16)0.f; h1h[1][tid] = (_Float16)0.f;
    }

    // static B-fragments: B[k][n] slot e at lane (16*kg + n): k = 32kt+8kg+e
    v8h Bhh0[4], Bih1[4], Bhh1[4];
#pragma unroll
    for (int kt = 0; kt < 4; ++kt) {
        v8h b0v, b1v, b2v;
#pragma unroll
        for (int e = 0; e < 8; ++e) {
            const int k = kt * 32 + kg * 8 + e;
            b0v[e] = (_Float16)W_hh[k * HID + jcol];
            b1v[e] = (_Float16)W_ih[HID * HID + k * HID + jcol];
            b2v[e] = (_Float16)W_hh[HID * HID + k * HID + jcol];
        }
        Bhh0[kt] = b0v; Bih1[kt] = b1v; Bhh1[kt] = b2v;
    }
    const float b1r = bias[HID + jcol];

    __syncthreads();                                 // xids + zeroed h visible

    // z-ring (depth 2): layer-0 input gather Y[tok][jcol]
    _Float16 zA = Y[(size_t)xids[0] * HID + jcol];
    _Float16 zB = Y[(size_t)xids[min(1, lenm1)] * HID + jcol];

    int ph = 0, pf = 0;

#define DO_PHASE(RD, WR, ZREG)                                              \
    {                                                                       \
        const uint4* h0p = (const uint4*)&h0h[RD][0];                       \
        const uint4* h1p = (const uint4*)&h1h[RD][0];                       \
        v8h A0[4], A1[4];                                                   \
        _Pragma("unroll")                                                   \
        for (int kt = 0; kt < 4; ++kt) {                                    \
            A0[kt] = BC8(h0p[kt * 4 + kg]);                                 \
            A1[kt] = BC8(h1p[kt * 4 + kg]);                                 \
        }                                                                   \
        const float zc = (float)ZREG;                                       \
        {                                                                   \
            const int tn = xids[min(ph + 2, lenm1)];                        \
            ZREG = Y[(size_t)tn * HID + jcol];                              \
        }                                                                   \
        v4f c0 = {0.f, 0.f, 0.f, 0.f};                                      \
        v4f c1 = {0.f, 0.f, 0.f, 0.f};                                      \
        _Pragma("unroll")                                                   \
        for (int kt = 0; kt < 4; ++kt)                                      \
            c0 = __builtin_amdgcn_mfma_f32_16x16x32_f16(A0[kt], Bhh0[kt], c0, 0, 0, 0); \
        _Pragma("unroll")                                                   \
        for (int kt = 0; kt < 4; ++kt)                                      \
            c1 = __builtin_amdgcn_mfma_f32_16x16x32_f16(A0[kt], Bih1[kt], c1, 0, 0, 0); \
        _Pragma("unroll")                                                   \
        for (int kt = 0; kt < 4; ++kt)                                      \
            c1 = __builtin_amdgcn_mfma_f32_16x16x32_f16(A1[kt], Bhh1[kt], c1, 0, 0, 0); \
        const float t0 = fast_tanh(c0.x + zc);                              \
        const float t1 = fast_tanh(c1.x + b1r);                             \
        if (kg == 0) {                                                      \
            if (ph < len) h0h[WR][jcol] = (_Float16)t0;                     \
            if (ph >= 1)  h1h[WR][jcol] = (_Float16)t1;                     \
        }                                                                   \
        __syncthreads();                                                    \
    }

    for (;;) {
        DO_PHASE(0, 1, zA)
        ++ph;
        if (ph > len) { pf = 1; break; }
        DO_PHASE(1, 0, zB)
        ++ph;
        if (ph > len) { pf = 0; break; }
    }
#undef DO_PHASE

    // classifier: out[b] = sigmoid(h1(len-1) . cls_w + cls_b)
    if (tid < HID) red[tid] = (float)h1h[pf][tid] * cls_w[tid];
    __syncthreads();
    if (tid == 0) {
        float s = 0.f;
        for (int i = 0; i < HID; ++i) s += red[i];
        s += cls_b[0];
        out[b] = fast_rcp(1.0f + __expf(-s));
    }
}

extern "C" void kernel_launch(void* const* d_in, const int* in_sizes, int n_in,
                              void* d_out, int out_size, void* d_ws, size_t ws_size,
                              hipStream_t stream) {
    const int*   x       = (const int*)  d_in[0];
    const int*   lengths = (const int*)  d_in[1];
    const float* emb     = (const float*)d_in[2];
    const float* W_ih    = (const float*)d_in[3];
    const float* W_hh    = (const float*)d_in[4];
    const float* bias    = (const float*)d_in[5];
    const float* cls_w   = (const float*)d_in[6];
    const float* cls_b   = (const float*)d_in[7];
    float*       out     = (float*)      d_out;

    _Float16* Yws = (_Float16*)d_ws;     // 50000*128*2 B = 12.8 MB

    emb_proj_kernel<<<2048, NTHR, 0, stream>>>(emb, W_ih, bias, Yws);
    rnn_mfma_kernel<<<BATCH, NTHR, 0, stream>>>(
        x, lengths, Yws, W_ih, W_hh, bias, cls_w, cls_b, out);
}